// Round 2
// baseline (679.761 us; speedup 1.0000x reference)
//
#include <hip/hip_runtime.h>
#include <hip/hip_bf16.h>
#include <math.h>

#define SEQ 2048
#define BATCH 4
#define HDIM 256
#define NHEAD 4
#define DH 64
#define FFN_DIM 1024
#define MTOT (BATCH*SEQ)   // 8192
#define WIN 32

typedef __attribute__((ext_vector_type(8))) short bf16x8;
typedef __attribute__((ext_vector_type(4))) float f32x4;

__device__ __forceinline__ float b2f(unsigned short u) {
    union { unsigned int i; float f; } v; v.i = ((unsigned int)u) << 16; return v.f;
}

// ---------------------------------------------------------------------------
// f32 -> bf16 convert (RN). Each thread converts 8 elements. n8 = n/8.
// ---------------------------------------------------------------------------
__global__ __launch_bounds__(256)
void cvt_kernel(const float* __restrict__ src, __hip_bfloat16* __restrict__ dst, int n8)
{
    int i = blockIdx.x * 256 + threadIdx.x;
    if (i >= n8) return;
    const float4* s = (const float4*)src + 2 * (size_t)i;
    float4 a = s[0], b = s[1];
    union { bf16x8 v; __hip_bfloat16 e[8]; } u;
    u.e[0] = __float2bfloat16(a.x); u.e[1] = __float2bfloat16(a.y);
    u.e[2] = __float2bfloat16(a.z); u.e[3] = __float2bfloat16(a.w);
    u.e[4] = __float2bfloat16(b.x); u.e[5] = __float2bfloat16(b.y);
    u.e[6] = __float2bfloat16(b.z); u.e[7] = __float2bfloat16(b.w);
    *(bf16x8*)((short*)dst + 8 * (size_t)i) = u.v;
}

// ---------------------------------------------------------------------------
// GEMM: C[M,N] = A[M,K] @ W[N,K]^T  (bf16 inputs, K-contiguous, fp32 acc)
// MODE 0: hbuf = alpha*C + PE(row%SEQ, col)       (fp32 out)
// MODE 1: obf  = bf16(C + bias)                    bias fp32
// MODE 2: obf  = bf16(relu(C + bias))
// MODE 3: hbuf += C + bias   (bias may be nullptr -> 0)
// MODE 4: of32 = C + bias                          (fp32 out, d_out)
// Block tile 128x64, 4 waves (2x2), wave tile 64x32, K-step 32.
// Grid: (N/64, M/128). M=8192, N%64==0, K%32==0.
// ---------------------------------------------------------------------------
template<int MODE>
__global__ __launch_bounds__(256)
void gemm_tn(const __hip_bfloat16* __restrict__ A,
             const __hip_bfloat16* __restrict__ W,
             const float* __restrict__ bias,
             float* __restrict__ hbuf,
             __hip_bfloat16* __restrict__ obf,
             float* __restrict__ of32,
             int N, int K, int lda, int ldw, float alpha)
{
    int tid  = threadIdx.x;
    int wave = tid >> 6, lane = tid & 63;
    int wm = wave >> 1, wn = wave & 1;
    int rowBase = blockIdx.y * 128 + wm * 64;
    int colBase = blockIdx.x * 64  + wn * 32;
    int lr = lane & 15;          // row within 16-tile (A) / col (B)
    int lk = (lane >> 4) * 8;    // k offset within 32-chunk

    const short* pa = (const short*)A + (size_t)(rowBase + lr) * lda + lk;
    const short* pb = (const short*)W + (size_t)(colBase + lr) * ldw + lk;

    f32x4 acc[4][2];
    #pragma unroll
    for (int mt = 0; mt < 4; mt++)
        #pragma unroll
        for (int nt = 0; nt < 2; nt++)
            acc[mt][nt] = (f32x4){0.f, 0.f, 0.f, 0.f};

    for (int k0 = 0; k0 < K; k0 += 32) {
        bf16x8 af[4], bfr[2];
        #pragma unroll
        for (int mt = 0; mt < 4; mt++)
            af[mt] = *(const bf16x8*)(pa + (size_t)mt * 16 * lda);
        #pragma unroll
        for (int nt = 0; nt < 2; nt++)
            bfr[nt] = *(const bf16x8*)(pb + (size_t)nt * 16 * ldw);
        #pragma unroll
        for (int mt = 0; mt < 4; mt++)
            #pragma unroll
            for (int nt = 0; nt < 2; nt++)
                acc[mt][nt] = __builtin_amdgcn_mfma_f32_16x16x32_bf16(
                    af[mt], bfr[nt], acc[mt][nt], 0, 0, 0);
        pa += 32;
        pb += 32;
    }

    // C/D layout: col = lane&15, row = (lane>>4)*4 + reg.
    int cq = lane >> 4, cc = lane & 15;
    #pragma unroll
    for (int mt = 0; mt < 4; mt++) {
        #pragma unroll
        for (int nt = 0; nt < 2; nt++) {
            int col = colBase + nt * 16 + cc;
            float bv = 0.f;
            if (MODE != 0) bv = bias ? bias[col] : 0.f;
            #pragma unroll
            for (int r = 0; r < 4; r++) {
                int row = rowBase + mt * 16 + cq * 4 + r;
                float c = acc[mt][nt][r];
                if (MODE == 0) {
                    int s  = row & (SEQ - 1);
                    int i2 = col & ~1;
                    float freq = expf((float)i2 * (-9.210340371976184f / 256.0f));
                    float arg  = (float)s * freq;
                    float pe   = (col & 1) ? cosf(arg) : sinf(arg);
                    hbuf[(size_t)row * HDIM + col] = alpha * c + pe;
                } else if (MODE == 1 || MODE == 2) {
                    c += bv;
                    if (MODE == 2) c = fmaxf(c, 0.f);
                    obf[(size_t)row * N + col] = __float2bfloat16(c);
                } else if (MODE == 3) {
                    hbuf[(size_t)row * HDIM + col] += c + bv;
                } else { // MODE 4
                    of32[(size_t)row * N + col] = c + bv;
                }
            }
        }
    }
}

// ---------------------------------------------------------------------------
// LayerNorm: fp32 h row (256) -> bf16 normalized row. One wave per row.
// g, b are fp32.
// ---------------------------------------------------------------------------
__global__ __launch_bounds__(256)
void ln_kernel(const float* __restrict__ h,
               const float* __restrict__ g,
               const float* __restrict__ b,
               __hip_bfloat16* __restrict__ o)
{
    int row  = blockIdx.x * 4 + (threadIdx.x >> 6);
    int lane = threadIdx.x & 63;
    const float4 xv = ((const float4*)(h + (size_t)row * HDIM))[lane];
    float s = xv.x + xv.y + xv.z + xv.w;
    #pragma unroll
    for (int off = 32; off >= 1; off >>= 1) s += __shfl_xor(s, off);
    float mu = s * (1.0f / 256.0f);
    float d0 = xv.x - mu, d1 = xv.y - mu, d2 = xv.z - mu, d3 = xv.w - mu;
    float v = d0 * d0 + d1 * d1 + d2 * d2 + d3 * d3;
    #pragma unroll
    for (int off = 32; off >= 1; off >>= 1) v += __shfl_xor(v, off);
    float rstd = rsqrtf(v * (1.0f / 256.0f) + 1e-5f);
    int c = lane * 4;
    const float4 gv = *(const float4*)(g + c);
    const float4 bv = *(const float4*)(b + c);
    __hip_bfloat16* op = o + (size_t)row * HDIM + c;
    op[0] = __float2bfloat16(d0 * rstd * gv.x + bv.x);
    op[1] = __float2bfloat16(d1 * rstd * gv.y + bv.y);
    op[2] = __float2bfloat16(d2 * rstd * gv.z + bv.z);
    op[3] = __float2bfloat16(d3 * rstd * gv.w + bv.w);
}

// ---------------------------------------------------------------------------
// Banded attention. qkv layout [B, S, 3*H], channel = section*H + head*64 + d.
// One thread per query; scores in LDS; fp32 softmax; scale 1/8.
// Block = 64 threads (one wave) = 64 consecutive queries of one (b, head).
// ---------------------------------------------------------------------------
__global__ __launch_bounds__(64)
void attn_kernel(const __hip_bfloat16* __restrict__ qkv,
                 __hip_bfloat16* __restrict__ o)
{
    __shared__ float sc[65][64];
    int tid  = threadIdx.x;
    int t    = blockIdx.x * 64 + tid;
    int b    = t >> 13;
    int head = (t >> 11) & 3;
    int i    = t & (SEQ - 1);

    const short* qp = (const short*)qkv + ((size_t)((b << 11) | i)) * 768 + head * 64;
    float q[64];
    #pragma unroll
    for (int c = 0; c < 8; c++) {
        bf16x8 v = *(const bf16x8*)(qp + c * 8);
        #pragma unroll
        for (int j = 0; j < 8; j++) q[c * 8 + j] = b2f((unsigned short)v[j]);
    }

    int jlo = (i > WIN) ? (i - WIN) : 0;
    int jhi = (i + WIN < SEQ) ? (i + WIN) : (SEQ - 1);
    int nj  = jhi - jlo + 1;

    const short* kb = (const short*)qkv + ((size_t)b << 11) * 768 + HDIM + head * 64;
    float m = -1e30f;
    for (int jj = 0; jj < nj; jj++) {
        const short* kp = kb + (size_t)(jlo + jj) * 768;
        float s = 0.f;
        #pragma unroll
        for (int c = 0; c < 8; c++) {
            bf16x8 kv = *(const bf16x8*)(kp + c * 8);
            #pragma unroll
            for (int j = 0; j < 8; j++) s += q[c * 8 + j] * b2f((unsigned short)kv[j]);
        }
        s *= 0.125f;
        sc[jj][tid] = s;
        m = fmaxf(m, s);
    }

    float d = 0.f;
    for (int jj = 0; jj < nj; jj++) d += __expf(sc[jj][tid] - m);
    float inv = 1.0f / d;

    float oa[64];
    #pragma unroll
    for (int l = 0; l < 64; l++) oa[l] = 0.f;
    const short* vb = kb + HDIM;
    for (int jj = 0; jj < nj; jj++) {
        float p = __expf(sc[jj][tid] - m) * inv;
        const short* vp = vb + (size_t)(jlo + jj) * 768;
        #pragma unroll
        for (int c = 0; c < 8; c++) {
            bf16x8 vv = *(const bf16x8*)(vp + c * 8);
            #pragma unroll
            for (int j = 0; j < 8; j++) oa[c * 8 + j] += p * b2f((unsigned short)vv[j]);
        }
    }

    __hip_bfloat16* op = o + ((size_t)((b << 11) | i)) * HDIM + head * 64;
    #pragma unroll
    for (int l = 0; l < 64; l++) op[l] = __float2bfloat16(oa[l]);
}

// ---------------------------------------------------------------------------
extern "C" void kernel_launch(void* const* d_in, const int* in_sizes, int n_in,
                              void* d_out, int out_size, void* d_ws, size_t ws_size,
                              hipStream_t stream)
{
    const float* x     = (const float*)d_in[0];
    const float* w_in  = (const float*)d_in[1];
    const float* w_out = (const float*)d_in[2];
    const float* b_out = (const float*)d_in[3];
    const float* qkv_w = (const float*)d_in[4];
    const float* qkv_b = (const float*)d_in[5];
    const float* out_w = (const float*)d_in[6];
    const float* out_b = (const float*)d_in[7];
    const float* ln1_g = (const float*)d_in[8];
    const float* ln1_b = (const float*)d_in[9];
    const float* ln2_g = (const float*)d_in[10];
    const float* ln2_b = (const float*)d_in[11];
    const float* ff1_w = (const float*)d_in[12];
    const float* ff1_b = (const float*)d_in[13];
    const float* ff2_w = (const float*)d_in[14];
    const float* ff2_b = (const float*)d_in[15];
    const float* lnf_g = (const float*)d_in[16];
    const float* lnf_b = (const float*)d_in[17];

    char* ws = (char*)d_ws;
    // [0, 8M)       : h, fp32 residual (8192x256x4 = 8,388,608)
    // [8M, 12M)     : xn (LN out) / att (attn out), bf16 (4,194,304)
    // [12M, 24M)    : buf: qkvb (12,582,912) / x_bf16 (4MB) / ffb chunk (8MB)
    // [24M, 28.7M)  : bf16 weight arena (4,980,736)
    float*          h    = (float*)ws;
    __hip_bfloat16* xn   = (__hip_bfloat16*)(ws + 8388608);
    __hip_bfloat16* att  = xn;  // alias: xn consumed by QKV gemm before attn writes
    __hip_bfloat16* buf  = (__hip_bfloat16*)(ws + 12582912);
    __hip_bfloat16* xb   = buf;                     // x_bf16, consumed first
    __hip_bfloat16* qkvb = buf;                     // per-layer qkv
    __hip_bfloat16* ffb  = buf;                     // ffn hidden chunk [8192,512]
    __hip_bfloat16* wb   = (__hip_bfloat16*)(ws + 25165824);

    __hip_bfloat16* w_in_b  = wb;                    //  65,536
    __hip_bfloat16* w_out_b = wb + 65536;            //  65,536
    __hip_bfloat16* qkv_w_b = wb + 131072;           // 589,824
    __hip_bfloat16* out_w_b = wb + 720896;           // 196,608
    __hip_bfloat16* ff1_w_b = wb + 917504;           // 786,432
    __hip_bfloat16* ff2_w_b = wb + 1703936;          // 786,432

    dim3 blk(256);
    #define CVT(src, dst, n) cvt_kernel<<<((n)/8 + 255) / 256, blk, 0, stream>>>(src, dst, (n)/8)
    CVT(w_in,  w_in_b,  65536);
    CVT(w_out, w_out_b, 65536);
    CVT(qkv_w, qkv_w_b, 589824);
    CVT(out_w, out_w_b, 196608);
    CVT(ff1_w, ff1_w_b, 786432);
    CVT(ff2_w, ff2_w_b, 786432);
    CVT(x,     xb,      2097152);
    #undef CVT

    dim3 gN256(4, 64), gN768(12, 64), gN512(8, 64);

    // h = 16 * (x @ w_in^T) + PE
    gemm_tn<0><<<gN256, blk, 0, stream>>>(xb, w_in_b, nullptr, h, nullptr, nullptr,
                                          HDIM, HDIM, HDIM, HDIM, 16.0f);

    for (int l = 0; l < 3; l++) {
        ln_kernel<<<MTOT / 4, blk, 0, stream>>>(h, ln1_g + l * HDIM, ln1_b + l * HDIM, xn);
        gemm_tn<1><<<gN768, blk, 0, stream>>>(xn, qkv_w_b + (size_t)l * 768 * HDIM,
                                              qkv_b + l * 768, nullptr, qkvb, nullptr,
                                              768, HDIM, HDIM, HDIM, 0.f);
        attn_kernel<<<(BATCH * NHEAD * SEQ) / 64, dim3(64), 0, stream>>>(qkvb, att);
        gemm_tn<3><<<gN256, blk, 0, stream>>>(att, out_w_b + (size_t)l * HDIM * HDIM,
                                              out_b + l * HDIM, h, nullptr, nullptr,
                                              HDIM, HDIM, HDIM, HDIM, 0.f);
        ln_kernel<<<MTOT / 4, blk, 0, stream>>>(h, ln2_g + l * HDIM, ln2_b + l * HDIM, xn);
        // FFN in two 512-wide chunks (hidden chunk buffer reused)
        for (int c = 0; c < 2; c++) {
            gemm_tn<2><<<gN512, blk, 0, stream>>>(
                xn, ff1_w_b + (size_t)l * FFN_DIM * HDIM + (size_t)c * 512 * HDIM,
                ff1_b + l * FFN_DIM + c * 512, nullptr, ffb, nullptr,
                512, HDIM, HDIM, HDIM, 0.f);
            gemm_tn<3><<<gN256, blk, 0, stream>>>(
                ffb, ff2_w_b + (size_t)l * HDIM * FFN_DIM + (size_t)c * 512,
                (c == 0) ? (ff2_b + l * HDIM) : nullptr, h, nullptr, nullptr,
                HDIM, 512, 512, FFN_DIM, 0.f);
        }
    }

    ln_kernel<<<MTOT / 4, blk, 0, stream>>>(h, lnf_g, lnf_b, xn);
    gemm_tn<4><<<gN256, blk, 0, stream>>>(xn, w_out_b, b_out, nullptr, nullptr,
                                          (float*)d_out, HDIM, HDIM, HDIM, HDIM, 0.f);
}

// Round 3
// 674.241 us; speedup vs baseline: 1.0082x; 1.0082x over previous
//
#include <hip/hip_runtime.h>
#include <hip/hip_bf16.h>
#include <math.h>

#define SEQ 2048
#define BATCH 4
#define HDIM 256
#define NHEAD 4
#define DH 64
#define FFN_DIM 1024
#define MTOT (BATCH*SEQ)   // 8192
#define WIN 32

typedef __attribute__((ext_vector_type(8))) short bf16x8;
typedef __attribute__((ext_vector_type(4))) float f32x4;

__device__ __forceinline__ float b2f(unsigned short u) {
    union { unsigned int i; float f; } v; v.i = ((unsigned int)u) << 16; return v.f;
}

// ---------------------------------------------------------------------------
// Fused f32 -> bf16 convert of all weights + x. One launch.
// Weight arena layout (element offsets): w_in 0, w_out 65536, qkv_w 131072,
// out_w 720896, ff1_w 917504, ff2_w 1703936 (end 2490368). x -> xb separately.
// Each thread converts 8 elements; 4587520 elems total -> 573440 items.
// ---------------------------------------------------------------------------
__global__ __launch_bounds__(256)
void cvt_all(const float* __restrict__ w_in, const float* __restrict__ w_out,
             const float* __restrict__ qkv_w, const float* __restrict__ out_w,
             const float* __restrict__ ff1_w, const float* __restrict__ ff2_w,
             const float* __restrict__ x,
             __hip_bfloat16* __restrict__ wb, __hip_bfloat16* __restrict__ xb)
{
    int i = blockIdx.x * 256 + threadIdx.x;
    if (i >= 573440) return;
    size_t e = (size_t)i * 8;
    const float* src;
    __hip_bfloat16* dst;
    if (e < 720896) {
        if (e < 65536)       { src = w_in  + e;            dst = wb + e; }
        else if (e < 131072) { src = w_out + (e - 65536);  dst = wb + e; }
        else                 { src = qkv_w + (e - 131072); dst = wb + e; }
    } else if (e < 917504)   { src = out_w + (e - 720896); dst = wb + e; }
    else if (e < 1703936)    { src = ff1_w + (e - 917504); dst = wb + e; }
    else if (e < 2490368)    { src = ff2_w + (e - 1703936); dst = wb + e; }
    else                     { src = x + (e - 2490368);    dst = xb + (e - 2490368); }

    const float4* s4 = (const float4*)src;
    float4 a = s4[0], b = s4[1];
    union { bf16x8 v; __hip_bfloat16 el[8]; } u;
    u.el[0] = __float2bfloat16(a.x); u.el[1] = __float2bfloat16(a.y);
    u.el[2] = __float2bfloat16(a.z); u.el[3] = __float2bfloat16(a.w);
    u.el[4] = __float2bfloat16(b.x); u.el[5] = __float2bfloat16(b.y);
    u.el[6] = __float2bfloat16(b.z); u.el[7] = __float2bfloat16(b.w);
    *(bf16x8*)dst = u.v;
}

// ---------------------------------------------------------------------------
// GEMM: C[M,N] = A[M,K] @ W[N,K]^T  (bf16 inputs, K-contiguous, fp32 acc)
// MODE 0: hbuf = alpha*C + PE(row%SEQ, col)       (fp32 out)
// MODE 1: obf  = bf16(C + bias)                    bias fp32
// MODE 2: obf  = bf16(relu(C + bias))
// MODE 3: hbuf += C + bias   (bias may be nullptr -> 0)
// MODE 4: of32 = C + bias                          (fp32 out, d_out)
// Block tile 128x64, 4 waves (2x2), wave tile 64x32, K-step 32.
// ---------------------------------------------------------------------------
template<int MODE>
__global__ __launch_bounds__(256)
void gemm_tn(const __hip_bfloat16* __restrict__ A,
             const __hip_bfloat16* __restrict__ W,
             const float* __restrict__ bias,
             float* __restrict__ hbuf,
             __hip_bfloat16* __restrict__ obf,
             float* __restrict__ of32,
             int N, int K, int lda, int ldw, float alpha)
{
    int tid  = threadIdx.x;
    int wave = tid >> 6, lane = tid & 63;
    int wm = wave >> 1, wn = wave & 1;
    int rowBase = blockIdx.y * 128 + wm * 64;
    int colBase = blockIdx.x * 64  + wn * 32;
    int lr = lane & 15;
    int lk = (lane >> 4) * 8;

    const short* pa = (const short*)A + (size_t)(rowBase + lr) * lda + lk;
    const short* pb = (const short*)W + (size_t)(colBase + lr) * ldw + lk;

    f32x4 acc[4][2];
    #pragma unroll
    for (int mt = 0; mt < 4; mt++)
        #pragma unroll
        for (int nt = 0; nt < 2; nt++)
            acc[mt][nt] = (f32x4){0.f, 0.f, 0.f, 0.f};

    for (int k0 = 0; k0 < K; k0 += 32) {
        bf16x8 af[4], bfr[2];
        #pragma unroll
        for (int mt = 0; mt < 4; mt++)
            af[mt] = *(const bf16x8*)(pa + (size_t)mt * 16 * lda);
        #pragma unroll
        for (int nt = 0; nt < 2; nt++)
            bfr[nt] = *(const bf16x8*)(pb + (size_t)nt * 16 * ldw);
        #pragma unroll
        for (int mt = 0; mt < 4; mt++)
            #pragma unroll
            for (int nt = 0; nt < 2; nt++)
                acc[mt][nt] = __builtin_amdgcn_mfma_f32_16x16x32_bf16(
                    af[mt], bfr[nt], acc[mt][nt], 0, 0, 0);
        pa += 32;
        pb += 32;
    }

    int cq = lane >> 4, cc = lane & 15;
    #pragma unroll
    for (int mt = 0; mt < 4; mt++) {
        #pragma unroll
        for (int nt = 0; nt < 2; nt++) {
            int col = colBase + nt * 16 + cc;
            float bv = 0.f;
            if (MODE != 0) bv = bias ? bias[col] : 0.f;
            #pragma unroll
            for (int r = 0; r < 4; r++) {
                int row = rowBase + mt * 16 + cq * 4 + r;
                float c = acc[mt][nt][r];
                if (MODE == 0) {
                    int s  = row & (SEQ - 1);
                    int i2 = col & ~1;
                    float freq = expf((float)i2 * (-9.210340371976184f / 256.0f));
                    float arg  = (float)s * freq;
                    float pe   = (col & 1) ? cosf(arg) : sinf(arg);
                    hbuf[(size_t)row * HDIM + col] = alpha * c + pe;
                } else if (MODE == 1 || MODE == 2) {
                    c += bv;
                    if (MODE == 2) c = fmaxf(c, 0.f);
                    obf[(size_t)row * N + col] = __float2bfloat16(c);
                } else if (MODE == 3) {
                    hbuf[(size_t)row * HDIM + col] += c + bv;
                } else {
                    of32[(size_t)row * N + col] = c + bv;
                }
            }
        }
    }
}

// ---------------------------------------------------------------------------
// LayerNorm: fp32 h row (256) -> bf16 normalized row. One wave per row.
// ---------------------------------------------------------------------------
__global__ __launch_bounds__(256)
void ln_kernel(const float* __restrict__ h,
               const float* __restrict__ g,
               const float* __restrict__ b,
               __hip_bfloat16* __restrict__ o)
{
    int row  = blockIdx.x * 4 + (threadIdx.x >> 6);
    int lane = threadIdx.x & 63;
    const float4 xv = ((const float4*)(h + (size_t)row * HDIM))[lane];
    float s = xv.x + xv.y + xv.z + xv.w;
    #pragma unroll
    for (int off = 32; off >= 1; off >>= 1) s += __shfl_xor(s, off);
    float mu = s * (1.0f / 256.0f);
    float d0 = xv.x - mu, d1 = xv.y - mu, d2 = xv.z - mu, d3 = xv.w - mu;
    float v = d0 * d0 + d1 * d1 + d2 * d2 + d3 * d3;
    #pragma unroll
    for (int off = 32; off >= 1; off >>= 1) v += __shfl_xor(v, off);
    float rstd = rsqrtf(v * (1.0f / 256.0f) + 1e-5f);
    int c = lane * 4;
    const float4 gv = *(const float4*)(g + c);
    const float4 bv = *(const float4*)(b + c);
    __hip_bfloat16* op = o + (size_t)row * HDIM + c;
    op[0] = __float2bfloat16(d0 * rstd * gv.x + bv.x);
    op[1] = __float2bfloat16(d1 * rstd * gv.y + bv.y);
    op[2] = __float2bfloat16(d2 * rstd * gv.z + bv.z);
    op[3] = __float2bfloat16(d3 * rstd * gv.w + bv.w);
}

// ---------------------------------------------------------------------------
// Banded attention, wave-per-query. qkv [B,S,768], ch = sec*256 + head*64 + d.
// Block = 256 threads = 4 waves = 4 queries; grid = 32768/4 = 8192 blocks.
// Phase 1: lane j -> score for key jlo+j (full 64-dim dot; K rows L1-hot);
//          65th key via cross-lane shuffle reduction.
// Softmax: two wave shuffle reductions. p staged in per-wave LDS row.
// Phase 2: lane d -> output dim d; V loads coalesced; p broadcast from LDS.
// No __syncthreads: LDS rows are wave-private, same-wave DS ops are ordered.
// ---------------------------------------------------------------------------
__global__ __launch_bounds__(256)
void attn_kernel(const __hip_bfloat16* __restrict__ qkv,
                 __hip_bfloat16* __restrict__ o)
{
    __shared__ float pbuf[4][68];
    int wid  = threadIdx.x >> 6, lane = threadIdx.x & 63;
    int t    = blockIdx.x * 4 + wid;
    int b    = t >> 13;
    int head = (t >> 11) & 3;
    int i    = t & (SEQ - 1);

    const short* base = (const short*)qkv + ((size_t)b * SEQ) * 768 + head * 64;
    const short* qp = base + (size_t)i * 768;
    const short* kb = base + HDIM;
    const short* vb = base + 2 * HDIM;

    // full q per lane (broadcast loads, L1-hot)
    float q[64];
    #pragma unroll
    for (int c = 0; c < 8; c++) {
        bf16x8 v = *(const bf16x8*)(qp + c * 8);
        #pragma unroll
        for (int j = 0; j < 8; j++) q[c * 8 + j] = b2f((unsigned short)v[j]);
    }
    float qlane = b2f(((const unsigned short*)qp)[lane]);

    int jlo = (i > WIN) ? (i - WIN) : 0;
    int jhi = (i + WIN < SEQ) ? (i + WIN) : (SEQ - 1);
    int nj  = jhi - jlo + 1;            // 33..65
    bool has65 = (nj == 65);

    // phase 1: own-key dot (lane j -> key jlo+j)
    float s = -1e30f;
    if (lane < nj) {
        const short* kp = kb + (size_t)(jlo + lane) * 768;
        float acc = 0.f;
        #pragma unroll
        for (int c = 0; c < 8; c++) {
            bf16x8 kv = *(const bf16x8*)(kp + c * 8);
            #pragma unroll
            for (int j = 0; j < 8; j++) acc += q[c * 8 + j] * b2f((unsigned short)kv[j]);
        }
        s = acc * 0.125f;
    }
    // 65th key: cooperative dot, lane = d
    float s64 = -1e30f;
    if (has65) {
        float part = qlane * b2f((unsigned short)kb[(size_t)(jlo + 64) * 768 + lane]);
        #pragma unroll
        for (int off = 32; off >= 1; off >>= 1) part += __shfl_xor(part, off);
        s64 = part * 0.125f;
    }

    // softmax across the band
    float m = fmaxf(s, s64);
    #pragma unroll
    for (int off = 32; off >= 1; off >>= 1) m = fmaxf(m, __shfl_xor(m, off));
    float e = __expf(s - m);            // masked lanes: exp(-huge) = 0
    float tot = e;
    #pragma unroll
    for (int off = 32; off >= 1; off >>= 1) tot += __shfl_xor(tot, off);
    float e64 = has65 ? __expf(s64 - m) : 0.f;
    tot += e64;                          // s64 fully reduced -> uniform across lanes
    float inv = 1.0f / tot;
    pbuf[wid][lane] = e * inv;
    if (lane == 0) pbuf[wid][64] = e64 * inv;

    // phase 2: lane = d, o_d = sum_j p_j * V[jlo+j][d]
    float oacc = 0.f;
    const short* vp = vb + (size_t)jlo * 768 + lane;
    for (int jj = 0; jj < nj; jj++) {
        float p = pbuf[wid][jj];
        oacc += p * b2f((unsigned short)vp[(size_t)jj * 768]);
    }

    o[((size_t)(b * SEQ + i)) * HDIM + head * 64 + lane] = __float2bfloat16(oacc);
}

// ---------------------------------------------------------------------------
extern "C" void kernel_launch(void* const* d_in, const int* in_sizes, int n_in,
                              void* d_out, int out_size, void* d_ws, size_t ws_size,
                              hipStream_t stream)
{
    const float* x     = (const float*)d_in[0];
    const float* w_in  = (const float*)d_in[1];
    const float* w_out = (const float*)d_in[2];
    const float* b_out = (const float*)d_in[3];
    const float* qkv_w = (const float*)d_in[4];
    const float* qkv_b = (const float*)d_in[5];
    const float* out_w = (const float*)d_in[6];
    const float* out_b = (const float*)d_in[7];
    const float* ln1_g = (const float*)d_in[8];
    const float* ln1_b = (const float*)d_in[9];
    const float* ln2_g = (const float*)d_in[10];
    const float* ln2_b = (const float*)d_in[11];
    const float* ff1_w = (const float*)d_in[12];
    const float* ff1_b = (const float*)d_in[13];
    const float* ff2_w = (const float*)d_in[14];
    const float* ff2_b = (const float*)d_in[15];
    const float* lnf_g = (const float*)d_in[16];
    const float* lnf_b = (const float*)d_in[17];

    char* ws = (char*)d_ws;
    float*          h    = (float*)ws;                       // [0, 8M) fp32 residual
    __hip_bfloat16* xn   = (__hip_bfloat16*)(ws + 8388608);  // [8M, 12M) LN out
    __hip_bfloat16* att  = xn;                               // alias (xn consumed first)
    __hip_bfloat16* buf  = (__hip_bfloat16*)(ws + 12582912); // [12M, 24M) qkv/x/ffn
    __hip_bfloat16* xb   = buf;
    __hip_bfloat16* qkvb = buf;
    __hip_bfloat16* ffb  = buf;
    __hip_bfloat16* wb   = (__hip_bfloat16*)(ws + 25165824); // [24M, ~28.7M) weights

    dim3 blk(256);

    cvt_all<<<(573440 + 255) / 256, blk, 0, stream>>>(w_in, w_out, qkv_w, out_w,
                                                      ff1_w, ff2_w, x, wb, xb);

    __hip_bfloat16* w_in_b  = wb;
    __hip_bfloat16* w_out_b = wb + 65536;
    __hip_bfloat16* qkv_w_b = wb + 131072;
    __hip_bfloat16* out_w_b = wb + 720896;
    __hip_bfloat16* ff1_w_b = wb + 917504;
    __hip_bfloat16* ff2_w_b = wb + 1703936;

    dim3 gN256(4, 64), gN768(12, 64), gN512(8, 64);

    gemm_tn<0><<<gN256, blk, 0, stream>>>(xb, w_in_b, nullptr, h, nullptr, nullptr,
                                          HDIM, HDIM, HDIM, HDIM, 16.0f);

    for (int l = 0; l < 3; l++) {
        ln_kernel<<<MTOT / 4, blk, 0, stream>>>(h, ln1_g + l * HDIM, ln1_b + l * HDIM, xn);
        gemm_tn<1><<<gN768, blk, 0, stream>>>(xn, qkv_w_b + (size_t)l * 768 * HDIM,
                                              qkv_b + l * 768, nullptr, qkvb, nullptr,
                                              768, HDIM, HDIM, HDIM, 0.f);
        attn_kernel<<<(BATCH * NHEAD * SEQ) / 4, blk, 0, stream>>>(qkvb, att);
        gemm_tn<3><<<gN256, blk, 0, stream>>>(att, out_w_b + (size_t)l * HDIM * HDIM,
                                              out_b + l * HDIM, h, nullptr, nullptr,
                                              HDIM, HDIM, HDIM, HDIM, 0.f);
        ln_kernel<<<MTOT / 4, blk, 0, stream>>>(h, ln2_g + l * HDIM, ln2_b + l * HDIM, xn);
        for (int c = 0; c < 2; c++) {
            gemm_tn<2><<<gN512, blk, 0, stream>>>(
                xn, ff1_w_b + (size_t)l * FFN_DIM * HDIM + (size_t)c * 512 * HDIM,
                ff1_b + l * FFN_DIM + c * 512, nullptr, ffb, nullptr,
                512, HDIM, HDIM, HDIM, 0.f);
            gemm_tn<3><<<gN256, blk, 0, stream>>>(
                ffb, ff2_w_b + (size_t)l * HDIM * FFN_DIM + (size_t)c * 512,
                (c == 0) ? (ff2_b + l * HDIM) : nullptr, h, nullptr, nullptr,
                HDIM, 512, 512, FFN_DIM, 0.f);
        }
    }

    ln_kernel<<<MTOT / 4, blk, 0, stream>>>(h, lnf_g, lnf_b, xn);
    gemm_tn<4><<<gN256, blk, 0, stream>>>(xn, w_out_b, b_out, nullptr, nullptr,
                                          (float*)d_out, HDIM, HDIM, HDIM, HDIM, 0.f);
}

// Round 4
// 470.621 us; speedup vs baseline: 1.4444x; 1.4327x over previous
//
#include <hip/hip_runtime.h>
#include <hip/hip_bf16.h>
#include <math.h>

#define SEQ 2048
#define BATCH 4
#define HDIM 256
#define NHEAD 4
#define DH 64
#define FFN_DIM 1024
#define MTOT (BATCH*SEQ)   // 8192
#define WIN 32

typedef __attribute__((ext_vector_type(8))) short bf16x8;
typedef __attribute__((ext_vector_type(4))) float f32x4;

__device__ __forceinline__ float b2f(unsigned short u) {
    union { unsigned int i; float f; } v; v.i = ((unsigned int)u) << 16; return v.f;
}

// ---------------------------------------------------------------------------
// Fused f32 -> bf16 convert of all weights + x. One launch.
// ---------------------------------------------------------------------------
__global__ __launch_bounds__(256)
void cvt_all(const float* __restrict__ w_in, const float* __restrict__ w_out,
             const float* __restrict__ qkv_w, const float* __restrict__ out_w,
             const float* __restrict__ ff1_w, const float* __restrict__ ff2_w,
             const float* __restrict__ x,
             __hip_bfloat16* __restrict__ wb, __hip_bfloat16* __restrict__ xb)
{
    int i = blockIdx.x * 256 + threadIdx.x;
    if (i >= 573440) return;
    size_t e = (size_t)i * 8;
    const float* src;
    __hip_bfloat16* dst;
    if (e < 720896) {
        if (e < 65536)       { src = w_in  + e;            dst = wb + e; }
        else if (e < 131072) { src = w_out + (e - 65536);  dst = wb + e; }
        else                 { src = qkv_w + (e - 131072); dst = wb + e; }
    } else if (e < 917504)   { src = out_w + (e - 720896); dst = wb + e; }
    else if (e < 1703936)    { src = ff1_w + (e - 917504); dst = wb + e; }
    else if (e < 2490368)    { src = ff2_w + (e - 1703936); dst = wb + e; }
    else                     { src = x + (e - 2490368);    dst = xb + (e - 2490368); }

    const float4* s4 = (const float4*)src;
    float4 a = s4[0], b = s4[1];
    union { bf16x8 v; __hip_bfloat16 el[8]; } u;
    u.el[0] = __float2bfloat16(a.x); u.el[1] = __float2bfloat16(a.y);
    u.el[2] = __float2bfloat16(a.z); u.el[3] = __float2bfloat16(a.w);
    u.el[4] = __float2bfloat16(b.x); u.el[5] = __float2bfloat16(b.y);
    u.el[6] = __float2bfloat16(b.z); u.el[7] = __float2bfloat16(b.w);
    *(bf16x8*)dst = u.v;
}

// ---------------------------------------------------------------------------
// GEMM: C[M,N] = A[M,K] @ W[N,K]^T  (bf16 inputs, K-contiguous, fp32 acc)
// MODE 0: hbuf = alpha*C + PE;  1: obf=bf16(C+b);  2: obf=bf16(relu(C+b));
// MODE 3: hbuf += C + b;        4: of32 = C + b
// Block tile 128x64, 4 waves (2x2), wave tile 64x32, K-step 32.
// ---------------------------------------------------------------------------
template<int MODE>
__global__ __launch_bounds__(256)
void gemm_tn(const __hip_bfloat16* __restrict__ A,
             const __hip_bfloat16* __restrict__ W,
             const float* __restrict__ bias,
             float* __restrict__ hbuf,
             __hip_bfloat16* __restrict__ obf,
             float* __restrict__ of32,
             int N, int K, int lda, int ldw, float alpha)
{
    int tid  = threadIdx.x;
    int wave = tid >> 6, lane = tid & 63;
    int wm = wave >> 1, wn = wave & 1;
    int rowBase = blockIdx.y * 128 + wm * 64;
    int colBase = blockIdx.x * 64  + wn * 32;
    int lr = lane & 15;
    int lk = (lane >> 4) * 8;

    const short* pa = (const short*)A + (size_t)(rowBase + lr) * lda + lk;
    const short* pb = (const short*)W + (size_t)(colBase + lr) * ldw + lk;

    f32x4 acc[4][2];
    #pragma unroll
    for (int mt = 0; mt < 4; mt++)
        #pragma unroll
        for (int nt = 0; nt < 2; nt++)
            acc[mt][nt] = (f32x4){0.f, 0.f, 0.f, 0.f};

    for (int k0 = 0; k0 < K; k0 += 32) {
        bf16x8 af[4], bfr[2];
        #pragma unroll
        for (int mt = 0; mt < 4; mt++)
            af[mt] = *(const bf16x8*)(pa + (size_t)mt * 16 * lda);
        #pragma unroll
        for (int nt = 0; nt < 2; nt++)
            bfr[nt] = *(const bf16x8*)(pb + (size_t)nt * 16 * ldw);
        #pragma unroll
        for (int mt = 0; mt < 4; mt++)
            #pragma unroll
            for (int nt = 0; nt < 2; nt++)
                acc[mt][nt] = __builtin_amdgcn_mfma_f32_16x16x32_bf16(
                    af[mt], bfr[nt], acc[mt][nt], 0, 0, 0);
        pa += 32;
        pb += 32;
    }

    int cq = lane >> 4, cc = lane & 15;
    #pragma unroll
    for (int mt = 0; mt < 4; mt++) {
        #pragma unroll
        for (int nt = 0; nt < 2; nt++) {
            int col = colBase + nt * 16 + cc;
            float bv = 0.f;
            if (MODE != 0) bv = bias ? bias[col] : 0.f;
            #pragma unroll
            for (int r = 0; r < 4; r++) {
                int row = rowBase + mt * 16 + cq * 4 + r;
                float c = acc[mt][nt][r];
                if (MODE == 0) {
                    int s  = row & (SEQ - 1);
                    int i2 = col & ~1;
                    float freq = expf((float)i2 * (-9.210340371976184f / 256.0f));
                    float arg  = (float)s * freq;
                    float pe   = (col & 1) ? cosf(arg) : sinf(arg);
                    hbuf[(size_t)row * HDIM + col] = alpha * c + pe;
                } else if (MODE == 1 || MODE == 2) {
                    c += bv;
                    if (MODE == 2) c = fmaxf(c, 0.f);
                    obf[(size_t)row * N + col] = __float2bfloat16(c);
                } else if (MODE == 3) {
                    hbuf[(size_t)row * HDIM + col] += c + bv;
                } else {
                    of32[(size_t)row * N + col] = c + bv;
                }
            }
        }
    }
}

// ---------------------------------------------------------------------------
// LayerNorm: fp32 h row (256) -> bf16 normalized row. One wave per row.
// ---------------------------------------------------------------------------
__global__ __launch_bounds__(256)
void ln_kernel(const float* __restrict__ h,
               const float* __restrict__ g,
               const float* __restrict__ b,
               __hip_bfloat16* __restrict__ o)
{
    int row  = blockIdx.x * 4 + (threadIdx.x >> 6);
    int lane = threadIdx.x & 63;
    const float4 xv = ((const float4*)(h + (size_t)row * HDIM))[lane];
    float s = xv.x + xv.y + xv.z + xv.w;
    #pragma unroll
    for (int off = 32; off >= 1; off >>= 1) s += __shfl_xor(s, off);
    float mu = s * (1.0f / 256.0f);
    float d0 = xv.x - mu, d1 = xv.y - mu, d2 = xv.z - mu, d3 = xv.w - mu;
    float v = d0 * d0 + d1 * d1 + d2 * d2 + d3 * d3;
    #pragma unroll
    for (int off = 32; off >= 1; off >>= 1) v += __shfl_xor(v, off);
    float rstd = rsqrtf(v * (1.0f / 256.0f) + 1e-5f);
    int c = lane * 4;
    const float4 gv = *(const float4*)(g + c);
    const float4 bv = *(const float4*)(b + c);
    __hip_bfloat16* op = o + (size_t)row * HDIM + c;
    op[0] = __float2bfloat16(d0 * rstd * gv.x + bv.x);
    op[1] = __float2bfloat16(d1 * rstd * gv.y + bv.y);
    op[2] = __float2bfloat16(d2 * rstd * gv.z + bv.z);
    op[3] = __float2bfloat16(d3 * rstd * gv.w + bv.w);
}

// ---------------------------------------------------------------------------
// MFMA banded attention. One block = (b, head, 32-query tile).
// Band |j-i|<=32 => keys for the tile span klo=i0-32 .. i0+63 (96 slots) —
// the FULL band fits in the tile: exact softmax, no online rescaling.
// 4 waves: phase A wave (qh=w&1, kseg=w>>1) computes S[16q x 48k] via MFMA
// (Q,K frags dense 16B loads from global). Stats via in-wave shuffle + LDS
// combine across the 2 kseg waves. P (normalized, bf16) -> LDS.
// V staged to LDS transposed (XOR-swizzled: 2-way write conflicts = free).
// Phase B wave (qh=w&1, dseg=w>>1) computes O[16q x 32d] = P @ V.
// ---------------------------------------------------------------------------
__global__ __launch_bounds__(256)
void attn_mfma(const __hip_bfloat16* __restrict__ qkv,
               __hip_bfloat16* __restrict__ o)
{
    __shared__ __align__(16) __hip_bfloat16 Vt[64][128]; // [d][key^swz]
    __shared__ __align__(16) __hip_bfloat16 Pl[32][96];  // [q][key]
    __shared__ float stat_m[2][32], stat_s[2][32];

    int tid  = threadIdx.x;
    int wid  = tid >> 6, lane = tid & 63;
    int qh   = wid & 1, seg = wid >> 1;   // kseg (phase A) / dseg (phase B)
    int bh   = blockIdx.y;
    int b    = bh >> 2, h = bh & 3;
    int i0   = blockIdx.x * 32;
    int klo  = i0 - 32;

    const short* base = (const short*)qkv + (size_t)(b * SEQ) * 768 + h * 64;

    // ---- stage V^T into LDS (swizzled col' = key ^ ((d>>3)<<3)) ----
    {
        int rlane = tid >> 3;          // 0..31
        int m     = tid & 7;           // d-group
        int dpart = m * 8;
        #pragma unroll
        for (int rr = 0; rr < 3; rr++) {
            int row = rr * 32 + rlane; // key slot 0..95
            int j = klo + row;
            j = j < 0 ? 0 : (j > SEQ - 1 ? SEQ - 1 : j);
            union { bf16x8 v; short e[8]; } u;
            u.v = *(const bf16x8*)(base + (size_t)j * 768 + 512 + dpart);
            int colp = row ^ (m << 3);
            #pragma unroll
            for (int jj = 0; jj < 8; jj++)
                *(short*)&Vt[dpart + jj][colp] = u.e[jj];
        }
    }

    int lr = lane & 15, hi = lane >> 4;  // frag row/col, k-chunk
    int cc = lane & 15, quad = lane >> 4;
    int qoff = qh * 16 + quad * 4;       // local q row base for C/D regs

    // ---- phase A: S = Q K^T / 8 over this wave's 48 key slots ----
    bf16x8 qf[2];
    #pragma unroll
    for (int ds = 0; ds < 2; ds++)
        qf[ds] = *(const bf16x8*)(base + (size_t)(i0 + qh * 16 + lr) * 768
                                  + ds * 32 + hi * 8);
    f32x4 sacc[3];
    #pragma unroll
    for (int t = 0; t < 3; t++) {
        int j = klo + seg * 48 + t * 16 + lr;
        j = j < 0 ? 0 : (j > SEQ - 1 ? SEQ - 1 : j);
        const short* kp = base + (size_t)j * 768 + 256 + hi * 8;
        bf16x8 k0 = *(const bf16x8*)kp;
        bf16x8 k1 = *(const bf16x8*)(kp + 32);
        f32x4 a = (f32x4){0.f, 0.f, 0.f, 0.f};
        a = __builtin_amdgcn_mfma_f32_16x16x32_bf16(qf[0], k0, a, 0, 0, 0);
        a = __builtin_amdgcn_mfma_f32_16x16x32_bf16(qf[1], k1, a, 0, 0, 0);
        sacc[t] = a;
    }

    // mask + scale
    float s[3][4];
    #pragma unroll
    for (int t = 0; t < 3; t++) {
        int koff = seg * 48 + t * 16 + cc;
        int jj = klo + koff;
        #pragma unroll
        for (int r = 0; r < 4; r++) {
            int qr = qoff + r;
            int rel = koff - qr;         // jj - i + 32
            bool ok = (jj >= 0) && (jj < SEQ) && (rel >= 0) && (rel <= 64);
            s[t][r] = ok ? sacc[t][r] * 0.125f : -1e30f;
        }
    }

    // per-row partial max / sum over this wave's 48 cols
    float mrow[4], srow[4];
    #pragma unroll
    for (int r = 0; r < 4; r++)
        mrow[r] = fmaxf(fmaxf(s[0][r], s[1][r]), s[2][r]);
    #pragma unroll
    for (int off = 8; off >= 1; off >>= 1)
        #pragma unroll
        for (int r = 0; r < 4; r++)
            mrow[r] = fmaxf(mrow[r], __shfl_xor(mrow[r], off));
    #pragma unroll
    for (int r = 0; r < 4; r++)
        srow[r] = __expf(s[0][r] - mrow[r]) + __expf(s[1][r] - mrow[r])
                + __expf(s[2][r] - mrow[r]);
    #pragma unroll
    for (int off = 8; off >= 1; off >>= 1)
        #pragma unroll
        for (int r = 0; r < 4; r++)
            srow[r] += __shfl_xor(srow[r], off);
    if (cc == 0) {
        #pragma unroll
        for (int r = 0; r < 4; r++) {
            stat_m[seg][qoff + r] = mrow[r];
            stat_s[seg][qoff + r] = srow[r];
        }
    }
    __syncthreads();

    // combine halves -> final M, 1/sum per row; write normalized P
    float Mr[4], inv[4];
    #pragma unroll
    for (int r = 0; r < 4; r++) {
        float m0 = stat_m[0][qoff + r], m1 = stat_m[1][qoff + r];
        float M  = fmaxf(m0, m1);
        float dn = stat_s[0][qoff + r] * __expf(m0 - M)
                 + stat_s[1][qoff + r] * __expf(m1 - M);
        Mr[r] = M; inv[r] = 1.0f / dn;
    }
    #pragma unroll
    for (int t = 0; t < 3; t++)
        #pragma unroll
        for (int r = 0; r < 4; r++)
            Pl[qoff + r][seg * 48 + t * 16 + cc] =
                __float2bfloat16(__expf(s[t][r] - Mr[r]) * inv[r]);
    __syncthreads();

    // ---- phase B: O[16q x 32d] = P @ V  (A from Pl, B from swizzled Vt) ----
    f32x4 oacc[2];
    oacc[0] = (f32x4){0.f, 0.f, 0.f, 0.f};
    oacc[1] = (f32x4){0.f, 0.f, 0.f, 0.f};
    #pragma unroll
    for (int ks = 0; ks < 3; ks++) {
        int kk = ks * 32;
        bf16x8 pf = *(const bf16x8*)&Pl[qh * 16 + lr][kk + hi * 8];
        #pragma unroll
        for (int dt = 0; dt < 2; dt++) {
            int d = seg * 32 + dt * 16 + lr;
            int colb = (kk + hi * 8) ^ (((d >> 3) & 7) << 3);
            bf16x8 vf = *(const bf16x8*)&Vt[d][colb];
            oacc[dt] = __builtin_amdgcn_mfma_f32_16x16x32_bf16(pf, vf, oacc[dt], 0, 0, 0);
        }
    }

    #pragma unroll
    for (int dt = 0; dt < 2; dt++) {
        int col = h * 64 + seg * 32 + dt * 16 + cc;
        #pragma unroll
        for (int r = 0; r < 4; r++) {
            int row = b * SEQ + i0 + qoff + r;
            o[(size_t)row * HDIM + col] = __float2bfloat16(oacc[dt][r]);
        }
    }
}

// ---------------------------------------------------------------------------
extern "C" void kernel_launch(void* const* d_in, const int* in_sizes, int n_in,
                              void* d_out, int out_size, void* d_ws, size_t ws_size,
                              hipStream_t stream)
{
    const float* x     = (const float*)d_in[0];
    const float* w_in  = (const float*)d_in[1];
    const float* w_out = (const float*)d_in[2];
    const float* b_out = (const float*)d_in[3];
    const float* qkv_w = (const float*)d_in[4];
    const float* qkv_b = (const float*)d_in[5];
    const float* out_w = (const float*)d_in[6];
    const float* out_b = (const float*)d_in[7];
    const float* ln1_g = (const float*)d_in[8];
    const float* ln1_b = (const float*)d_in[9];
    const float* ln2_g = (const float*)d_in[10];
    const float* ln2_b = (const float*)d_in[11];
    const float* ff1_w = (const float*)d_in[12];
    const float* ff1_b = (const float*)d_in[13];
    const float* ff2_w = (const float*)d_in[14];
    const float* ff2_b = (const float*)d_in[15];
    const float* lnf_g = (const float*)d_in[16];
    const float* lnf_b = (const float*)d_in[17];

    char* ws = (char*)d_ws;
    float*          h    = (float*)ws;                       // [0, 8M) fp32 residual
    __hip_bfloat16* xn   = (__hip_bfloat16*)(ws + 8388608);  // [8M, 12M) LN out
    __hip_bfloat16* att  = xn;                               // alias (xn consumed first)
    __hip_bfloat16* buf  = (__hip_bfloat16*)(ws + 12582912); // [12M, 24M) qkv/x/ffn
    __hip_bfloat16* xb   = buf;
    __hip_bfloat16* qkvb = buf;
    __hip_bfloat16* ffb  = buf;
    __hip_bfloat16* wb   = (__hip_bfloat16*)(ws + 25165824); // [24M, ~28.7M) weights

    dim3 blk(256);

    cvt_all<<<(573440 + 255) / 256, blk, 0, stream>>>(w_in, w_out, qkv_w, out_w,
                                                      ff1_w, ff2_w, x, wb, xb);

    __hip_bfloat16* w_in_b  = wb;
    __hip_bfloat16* w_out_b = wb + 65536;
    __hip_bfloat16* qkv_w_b = wb + 131072;
    __hip_bfloat16* out_w_b = wb + 720896;
    __hip_bfloat16* ff1_w_b = wb + 917504;
    __hip_bfloat16* ff2_w_b = wb + 1703936;

    dim3 gN256(4, 64), gN768(12, 64), gN512(8, 64);
    dim3 gAttn(SEQ / 32, BATCH * NHEAD);   // (64, 16)

    gemm_tn<0><<<gN256, blk, 0, stream>>>(xb, w_in_b, nullptr, h, nullptr, nullptr,
                                          HDIM, HDIM, HDIM, HDIM, 16.0f);

    for (int l = 0; l < 3; l++) {
        ln_kernel<<<MTOT / 4, blk, 0, stream>>>(h, ln1_g + l * HDIM, ln1_b + l * HDIM, xn);
        gemm_tn<1><<<gN768, blk, 0, stream>>>(xn, qkv_w_b + (size_t)l * 768 * HDIM,
                                              qkv_b + l * 768, nullptr, qkvb, nullptr,
                                              768, HDIM, HDIM, HDIM, 0.f);
        attn_mfma<<<gAttn, blk, 0, stream>>>(qkvb, att);
        gemm_tn<3><<<gN256, blk, 0, stream>>>(att, out_w_b + (size_t)l * HDIM * HDIM,
                                              out_b + l * HDIM, h, nullptr, nullptr,
                                              HDIM, HDIM, HDIM, HDIM, 0.f);
        ln_kernel<<<MTOT / 4, blk, 0, stream>>>(h, ln2_g + l * HDIM, ln2_b + l * HDIM, xn);
        for (int c = 0; c < 2; c++) {
            gemm_tn<2><<<gN512, blk, 0, stream>>>(
                xn, ff1_w_b + (size_t)l * FFN_DIM * HDIM + (size_t)c * 512 * HDIM,
                ff1_b + l * FFN_DIM + c * 512, nullptr, ffb, nullptr,
                512, HDIM, HDIM, HDIM, 0.f);
            gemm_tn<3><<<gN256, blk, 0, stream>>>(
                ffb, ff2_w_b + (size_t)l * HDIM * FFN_DIM + (size_t)c * 512,
                (c == 0) ? (ff2_b + l * HDIM) : nullptr, h, nullptr, nullptr,
                HDIM, 512, 512, FFN_DIM, 0.f);
        }
    }

    ln_kernel<<<MTOT / 4, blk, 0, stream>>>(h, lnf_g, lnf_b, xn);
    gemm_tn<4><<<gN256, blk, 0, stream>>>(xn, w_out_b, b_out, nullptr, nullptr,
                                          (float*)d_out, HDIM, HDIM, HDIM, HDIM, 0.f);
}

// Round 5
// 420.082 us; speedup vs baseline: 1.6182x; 1.1203x over previous
//
#include <hip/hip_runtime.h>
#include <hip/hip_bf16.h>
#include <math.h>

#define SEQ 2048
#define BATCH 4
#define HDIM 256
#define NHEAD 4
#define DH 64
#define FFN_DIM 1024
#define MTOT (BATCH*SEQ)   // 8192
#define WIN 32

typedef __attribute__((ext_vector_type(8))) short bf16x8;
typedef __attribute__((ext_vector_type(4))) float f32x4;

__device__ __forceinline__ float b2f(unsigned short u) {
    union { unsigned int i; float f; } v; v.i = ((unsigned int)u) << 16; return v.f;
}

// ---------------------------------------------------------------------------
// Fused f32 -> bf16 convert of all weights + x. One launch.
// Arena element offsets: w_in 0, w_out 65536, qkv_w 131072, out_w 720896,
// ff1_w 917504, ff2_w 1703936 (end 2490368). x (2097152 elems) -> xb.
// ---------------------------------------------------------------------------
__global__ __launch_bounds__(256)
void cvt_all(const float* __restrict__ w_in, const float* __restrict__ w_out,
             const float* __restrict__ qkv_w, const float* __restrict__ out_w,
             const float* __restrict__ ff1_w, const float* __restrict__ ff2_w,
             const float* __restrict__ x,
             __hip_bfloat16* __restrict__ wb, __hip_bfloat16* __restrict__ xb)
{
    int i = blockIdx.x * 256 + threadIdx.x;
    if (i >= 573440) return;
    size_t e = (size_t)i * 8;
    const float* src;
    __hip_bfloat16* dst;
    if (e < 720896) {
        if (e < 65536)       { src = w_in  + e;            dst = wb + e; }
        else if (e < 131072) { src = w_out + (e - 65536);  dst = wb + e; }
        else                 { src = qkv_w + (e - 131072); dst = wb + e; }
    } else if (e < 917504)   { src = out_w + (e - 720896); dst = wb + e; }
    else if (e < 1703936)    { src = ff1_w + (e - 917504); dst = wb + e; }
    else if (e < 2490368)    { src = ff2_w + (e - 1703936); dst = wb + e; }
    else                     { src = x + (e - 2490368);    dst = xb + (e - 2490368); }

    const float4* s4 = (const float4*)src;
    float4 a = s4[0], b = s4[1];
    union { bf16x8 v; __hip_bfloat16 el[8]; } u;
    u.el[0] = __float2bfloat16(a.x); u.el[1] = __float2bfloat16(a.y);
    u.el[2] = __float2bfloat16(a.z); u.el[3] = __float2bfloat16(a.w);
    u.el[4] = __float2bfloat16(b.x); u.el[5] = __float2bfloat16(b.y);
    u.el[6] = __float2bfloat16(b.z); u.el[7] = __float2bfloat16(b.w);
    *(bf16x8*)dst = u.v;
}

// ---------------------------------------------------------------------------
// LN-fused GEMM: O[M,N] = LN(h)[M,256] @ W[N,256]^T (+bias, +relu...)
// Block: 128 rows x NT cols, 256 thr (4 waves 2x2), wave tile 64 x NT/2.
// Stage: wave w LNs rows w*32..w*32+31 (whole wave per row: 64xfloat4 load,
// shuffle-reduce mean/var) -> bf16 A_lds[128][280] (280: 16B-aligned rows,
// 12-bank row advance -> 2 lanes/bank on ds_read_b128 = free).
// MODE 1: obf = bf16(C+bias);  2: obf = bf16(relu(C+bias));  4: of32 = C+bias
// ---------------------------------------------------------------------------
template<int MODE, int NT>
__global__ __launch_bounds__(256)
void gemm_ln(const float* __restrict__ h,
             const float* __restrict__ g, const float* __restrict__ bln,
             const __hip_bfloat16* __restrict__ W,
             const float* __restrict__ bias,
             __hip_bfloat16* __restrict__ obf, float* __restrict__ of32,
             int N, int ldw)
{
    constexpr int NTW = NT / 32;               // 16-col tiles per wave
    __shared__ __align__(16) short A_lds[128][280];

    int tid = threadIdx.x, wave = tid >> 6, lane = tid & 63;
    int wm = wave >> 1, wn = wave & 1;
    int rowBase = blockIdx.y * 128;
    int colBase = blockIdx.x * NT + wn * (NT / 2);

    // ---- LN staging ----
    {
        float4 gv = *(const float4*)(g + lane * 4);
        float4 bv = *(const float4*)(bln + lane * 4);
        for (int rr = 0; rr < 32; rr += 4) {
            float4 xv[4];
            #pragma unroll
            for (int u = 0; u < 4; u++)
                xv[u] = *(const float4*)(h + (size_t)(rowBase + wave * 32 + rr + u) * HDIM
                                         + lane * 4);
            #pragma unroll
            for (int u = 0; u < 4; u++) {
                float s = xv[u].x + xv[u].y + xv[u].z + xv[u].w;
                #pragma unroll
                for (int off = 32; off >= 1; off >>= 1) s += __shfl_xor(s, off);
                float mu = s * (1.0f / 256.0f);
                float d0 = xv[u].x - mu, d1 = xv[u].y - mu;
                float d2 = xv[u].z - mu, d3 = xv[u].w - mu;
                float v = d0 * d0 + d1 * d1 + d2 * d2 + d3 * d3;
                #pragma unroll
                for (int off = 32; off >= 1; off >>= 1) v += __shfl_xor(v, off);
                float rstd = rsqrtf(v * (1.0f / 256.0f) + 1e-5f);
                union { short e[4]; uint2 w2; } o;
                o.e[0] = (short)(unsigned short)__bfloat16_as_ushort(
                            __float2bfloat16(d0 * rstd * gv.x + bv.x));
                o.e[1] = (short)(unsigned short)__bfloat16_as_ushort(
                            __float2bfloat16(d1 * rstd * gv.y + bv.y));
                o.e[2] = (short)(unsigned short)__bfloat16_as_ushort(
                            __float2bfloat16(d2 * rstd * gv.z + bv.z));
                o.e[3] = (short)(unsigned short)__bfloat16_as_ushort(
                            __float2bfloat16(d3 * rstd * gv.w + bv.w));
                *(uint2*)&A_lds[wave * 32 + rr + u][lane * 4] = o.w2;
            }
        }
    }
    __syncthreads();

    int lr = lane & 15, hi = lane >> 4;

    f32x4 acc[4][NTW];
    #pragma unroll
    for (int mt = 0; mt < 4; mt++)
        #pragma unroll
        for (int nt = 0; nt < NTW; nt++)
            acc[mt][nt] = (f32x4){0.f, 0.f, 0.f, 0.f};

    #pragma unroll
    for (int k0 = 0; k0 < 256; k0 += 32) {
        bf16x8 af[4], bfr[NTW];
        #pragma unroll
        for (int mt = 0; mt < 4; mt++)
            af[mt] = *(const bf16x8*)&A_lds[wm * 64 + mt * 16 + lr][k0 + hi * 8];
        #pragma unroll
        for (int nt = 0; nt < NTW; nt++)
            bfr[nt] = *(const bf16x8*)((const short*)W
                        + (size_t)(colBase + nt * 16 + lr) * ldw + k0 + hi * 8);
        #pragma unroll
        for (int mt = 0; mt < 4; mt++)
            #pragma unroll
            for (int nt = 0; nt < NTW; nt++)
                acc[mt][nt] = __builtin_amdgcn_mfma_f32_16x16x32_bf16(
                    af[mt], bfr[nt], acc[mt][nt], 0, 0, 0);
    }

    int cc = lane & 15, quad = lane >> 4;
    #pragma unroll
    for (int mt = 0; mt < 4; mt++) {
        #pragma unroll
        for (int nt = 0; nt < NTW; nt++) {
            int col = colBase + nt * 16 + cc;
            float bv = bias[col];
            #pragma unroll
            for (int r = 0; r < 4; r++) {
                int row = rowBase + wm * 64 + mt * 16 + quad * 4 + r;
                float c = acc[mt][nt][r] + bv;
                if (MODE == 2) c = fmaxf(c, 0.f);
                if (MODE == 4) of32[(size_t)row * N + col] = c;
                else           obf[(size_t)row * N + col] = __float2bfloat16(c);
            }
        }
    }
}

// ---------------------------------------------------------------------------
// Direct GEMM, 64x64 tile, 4 waves 2x2, wave tile 32x32 (2x2 of 16x16).
// Light VGPR (~60) -> high occupancy for the small-N latency-bound GEMMs.
// MODE 0: hbuf = alpha*C + PE(row%SEQ,col);  MODE 3: hbuf += C + bias
// ---------------------------------------------------------------------------
template<int MODE>
__global__ __launch_bounds__(256)
void gemm64(const __hip_bfloat16* __restrict__ A,
            const __hip_bfloat16* __restrict__ W,
            const float* __restrict__ bias,
            float* __restrict__ hbuf,
            int N, int K, int lda, int ldw, float alpha)
{
    int tid = threadIdx.x, wave = tid >> 6, lane = tid & 63;
    int wm = wave >> 1, wn = wave & 1;
    int rowBase = blockIdx.y * 64 + wm * 32;
    int colBase = blockIdx.x * 64 + wn * 32;
    int lr = lane & 15, hi = lane >> 4;

    const short* pa = (const short*)A + (size_t)(rowBase + lr) * lda + hi * 8;
    const short* pb = (const short*)W + (size_t)(colBase + lr) * ldw + hi * 8;

    f32x4 acc[2][2];
    #pragma unroll
    for (int mt = 0; mt < 2; mt++)
        #pragma unroll
        for (int nt = 0; nt < 2; nt++)
            acc[mt][nt] = (f32x4){0.f, 0.f, 0.f, 0.f};

    for (int k0 = 0; k0 < K; k0 += 32) {
        bf16x8 af[2], bfr[2];
        #pragma unroll
        for (int mt = 0; mt < 2; mt++)
            af[mt] = *(const bf16x8*)(pa + (size_t)mt * 16 * lda);
        #pragma unroll
        for (int nt = 0; nt < 2; nt++)
            bfr[nt] = *(const bf16x8*)(pb + (size_t)nt * 16 * ldw);
        #pragma unroll
        for (int mt = 0; mt < 2; mt++)
            #pragma unroll
            for (int nt = 0; nt < 2; nt++)
                acc[mt][nt] = __builtin_amdgcn_mfma_f32_16x16x32_bf16(
                    af[mt], bfr[nt], acc[mt][nt], 0, 0, 0);
        pa += 32;
        pb += 32;
    }

    int cc = lane & 15, quad = lane >> 4;
    #pragma unroll
    for (int mt = 0; mt < 2; mt++) {
        #pragma unroll
        for (int nt = 0; nt < 2; nt++) {
            int col = colBase + nt * 16 + cc;
            float bv = (MODE == 3) ? bias[col] : 0.f;
            #pragma unroll
            for (int r = 0; r < 4; r++) {
                int row = rowBase + mt * 16 + quad * 4 + r;
                float c = acc[mt][nt][r];
                if (MODE == 0) {
                    int s  = row & (SEQ - 1);
                    int i2 = col & ~1;
                    float freq = expf((float)i2 * (-9.210340371976184f / 256.0f));
                    float arg  = (float)s * freq;
                    float pe   = (col & 1) ? cosf(arg) : sinf(arg);
                    hbuf[(size_t)row * HDIM + col] = alpha * c + pe;
                } else {
                    hbuf[(size_t)row * HDIM + col] += c + bv;
                }
            }
        }
    }
}

// ---------------------------------------------------------------------------
// MFMA banded attention (unchanged from round 4). One block = (b, head, 32 q).
// ---------------------------------------------------------------------------
__global__ __launch_bounds__(256)
void attn_mfma(const __hip_bfloat16* __restrict__ qkv,
               __hip_bfloat16* __restrict__ o)
{
    __shared__ __align__(16) __hip_bfloat16 Vt[64][128];
    __shared__ __align__(16) __hip_bfloat16 Pl[32][96];
    __shared__ float stat_m[2][32], stat_s[2][32];

    int tid  = threadIdx.x;
    int wid  = tid >> 6, lane = tid & 63;
    int qh   = wid & 1, seg = wid >> 1;
    int bh   = blockIdx.y;
    int b    = bh >> 2, h = bh & 3;
    int i0   = blockIdx.x * 32;
    int klo  = i0 - 32;

    const short* base = (const short*)qkv + (size_t)(b * SEQ) * 768 + h * 64;

    {
        int rlane = tid >> 3;
        int m     = tid & 7;
        int dpart = m * 8;
        #pragma unroll
        for (int rr = 0; rr < 3; rr++) {
            int row = rr * 32 + rlane;
            int j = klo + row;
            j = j < 0 ? 0 : (j > SEQ - 1 ? SEQ - 1 : j);
            union { bf16x8 v; short e[8]; } u;
            u.v = *(const bf16x8*)(base + (size_t)j * 768 + 512 + dpart);
            int colp = row ^ (m << 3);
            #pragma unroll
            for (int jj = 0; jj < 8; jj++)
                *(short*)&Vt[dpart + jj][colp] = u.e[jj];
        }
    }

    int lr = lane & 15, hi = lane >> 4;
    int cc = lane & 15, quad = lane >> 4;
    int qoff = qh * 16 + quad * 4;

    bf16x8 qf[2];
    #pragma unroll
    for (int ds = 0; ds < 2; ds++)
        qf[ds] = *(const bf16x8*)(base + (size_t)(i0 + qh * 16 + lr) * 768
                                  + ds * 32 + hi * 8);
    f32x4 sacc[3];
    #pragma unroll
    for (int t = 0; t < 3; t++) {
        int j = klo + seg * 48 + t * 16 + lr;
        j = j < 0 ? 0 : (j > SEQ - 1 ? SEQ - 1 : j);
        const short* kp = base + (size_t)j * 768 + 256 + hi * 8;
        bf16x8 k0 = *(const bf16x8*)kp;
        bf16x8 k1 = *(const bf16x8*)(kp + 32);
        f32x4 a = (f32x4){0.f, 0.f, 0.f, 0.f};
        a = __builtin_amdgcn_mfma_f32_16x16x32_bf16(qf[0], k0, a, 0, 0, 0);
        a = __builtin_amdgcn_mfma_f32_16x16x32_bf16(qf[1], k1, a, 0, 0, 0);
        sacc[t] = a;
    }

    float s[3][4];
    #pragma unroll
    for (int t = 0; t < 3; t++) {
        int koff = seg * 48 + t * 16 + cc;
        int jj = klo + koff;
        #pragma unroll
        for (int r = 0; r < 4; r++) {
            int qr = qoff + r;
            int rel = koff - qr;
            bool ok = (jj >= 0) && (jj < SEQ) && (rel >= 0) && (rel <= 64);
            s[t][r] = ok ? sacc[t][r] * 0.125f : -1e30f;
        }
    }

    float mrow[4], srow[4];
    #pragma unroll
    for (int r = 0; r < 4; r++)
        mrow[r] = fmaxf(fmaxf(s[0][r], s[1][r]), s[2][r]);
    #pragma unroll
    for (int off = 8; off >= 1; off >>= 1)
        #pragma unroll
        for (int r = 0; r < 4; r++)
            mrow[r] = fmaxf(mrow[r], __shfl_xor(mrow[r], off));
    #pragma unroll
    for (int r = 0; r < 4; r++)
        srow[r] = __expf(s[0][r] - mrow[r]) + __expf(s[1][r] - mrow[r])
                + __expf(s[2][r] - mrow[r]);
    #pragma unroll
    for (int off = 8; off >= 1; off >>= 1)
        #pragma unroll
        for (int r = 0; r < 4; r++)
            srow[r] += __shfl_xor(srow[r], off);
    if (cc == 0) {
        #pragma unroll
        for (int r = 0; r < 4; r++) {
            stat_m[seg][qoff + r] = mrow[r];
            stat_s[seg][qoff + r] = srow[r];
        }
    }
    __syncthreads();

    float Mr[4], inv[4];
    #pragma unroll
    for (int r = 0; r < 4; r++) {
        float m0 = stat_m[0][qoff + r], m1 = stat_m[1][qoff + r];
        float M  = fmaxf(m0, m1);
        float dn = stat_s[0][qoff + r] * __expf(m0 - M)
                 + stat_s[1][qoff + r] * __expf(m1 - M);
        Mr[r] = M; inv[r] = 1.0f / dn;
    }
    #pragma unroll
    for (int t = 0; t < 3; t++)
        #pragma unroll
        for (int r = 0; r < 4; r++)
            Pl[qoff + r][seg * 48 + t * 16 + cc] =
                __float2bfloat16(__expf(s[t][r] - Mr[r]) * inv[r]);
    __syncthreads();

    f32x4 oacc[2];
    oacc[0] = (f32x4){0.f, 0.f, 0.f, 0.f};
    oacc[1] = (f32x4){0.f, 0.f, 0.f, 0.f};
    #pragma unroll
    for (int ks = 0; ks < 3; ks++) {
        int kk = ks * 32;
        bf16x8 pf = *(const bf16x8*)&Pl[qh * 16 + lr][kk + hi * 8];
        #pragma unroll
        for (int dt = 0; dt < 2; dt++) {
            int d = seg * 32 + dt * 16 + lr;
            int colb = (kk + hi * 8) ^ (((d >> 3) & 7) << 3);
            bf16x8 vf = *(const bf16x8*)&Vt[d][colb];
            oacc[dt] = __builtin_amdgcn_mfma_f32_16x16x32_bf16(pf, vf, oacc[dt], 0, 0, 0);
        }
    }

    #pragma unroll
    for (int dt = 0; dt < 2; dt++) {
        int col = h * 64 + seg * 32 + dt * 16 + cc;
        #pragma unroll
        for (int r = 0; r < 4; r++) {
            int row = b * SEQ + i0 + qoff + r;
            o[(size_t)row * HDIM + col] = __float2bfloat16(oacc[dt][r]);
        }
    }
}

// ---------------------------------------------------------------------------
extern "C" void kernel_launch(void* const* d_in, const int* in_sizes, int n_in,
                              void* d_out, int out_size, void* d_ws, size_t ws_size,
                              hipStream_t stream)
{
    const float* x     = (const float*)d_in[0];
    const float* w_in  = (const float*)d_in[1];
    const float* w_out = (const float*)d_in[2];
    const float* b_out = (const float*)d_in[3];
    const float* qkv_w = (const float*)d_in[4];
    const float* qkv_b = (const float*)d_in[5];
    const float* out_w = (const float*)d_in[6];
    const float* out_b = (const float*)d_in[7];
    const float* ln1_g = (const float*)d_in[8];
    const float* ln1_b = (const float*)d_in[9];
    const float* ln2_g = (const float*)d_in[10];
    const float* ln2_b = (const float*)d_in[11];
    const float* ff1_w = (const float*)d_in[12];
    const float* ff1_b = (const float*)d_in[13];
    const float* ff2_w = (const float*)d_in[14];
    const float* ff2_b = (const float*)d_in[15];
    const float* lnf_g = (const float*)d_in[16];
    const float* lnf_b = (const float*)d_in[17];

    char* ws = (char*)d_ws;                   // ws ~256 MB; generous layout:
    float*          h    = (float*)ws;                        // [0, 8M)
    __hip_bfloat16* qkvb = (__hip_bfloat16*)(ws + 8388608);   // [8M, 20M)
    __hip_bfloat16* att  = (__hip_bfloat16*)(ws + 20971520);  // [20M, 24M)
    __hip_bfloat16* ffb  = (__hip_bfloat16*)(ws + 25165824);  // [24M, 40M)
    __hip_bfloat16* wb   = (__hip_bfloat16*)(ws + 41943040);  // [40M, ~45M)
    __hip_bfloat16* xb   = (__hip_bfloat16*)(ws + 46923776);  // [~44.8M, +4M)

    __hip_bfloat16* w_in_b  = wb;
    __hip_bfloat16* w_out_b = wb + 65536;
    __hip_bfloat16* qkv_w_b = wb + 131072;
    __hip_bfloat16* out_w_b = wb + 720896;
    __hip_bfloat16* ff1_w_b = wb + 917504;
    __hip_bfloat16* ff2_w_b = wb + 1703936;

    dim3 blk(256);

    cvt_all<<<(573440 + 255) / 256, blk, 0, stream>>>(w_in, w_out, qkv_w, out_w,
                                                      ff1_w, ff2_w, x, wb, xb);

    // h = 16 * (x @ w_in^T) + PE
    gemm64<0><<<dim3(4, 128), blk, 0, stream>>>(xb, w_in_b, nullptr, h,
                                                HDIM, HDIM, HDIM, HDIM, 16.0f);

    for (int l = 0; l < 3; l++) {
        // qkv = LN1(h) @ qkv_w^T + qkv_b
        gemm_ln<1, 128><<<dim3(6, 64), blk, 0, stream>>>(
            h, ln1_g + l * HDIM, ln1_b + l * HDIM,
            qkv_w_b + (size_t)l * 768 * HDIM, qkv_b + l * 768,
            qkvb, nullptr, 768, HDIM);
        attn_mfma<<<dim3(SEQ / 32, BATCH * NHEAD), blk, 0, stream>>>(qkvb, att);
        // h += att @ out_w^T + out_b
        gemm64<3><<<dim3(4, 128), blk, 0, stream>>>(
            att, out_w_b + (size_t)l * HDIM * HDIM, out_b + l * HDIM, h,
            HDIM, HDIM, HDIM, HDIM, 0.f);
        // ffb = relu(LN2(h) @ ff1_w^T + ff1_b)
        gemm_ln<2, 128><<<dim3(8, 64), blk, 0, stream>>>(
            h, ln2_g + l * HDIM, ln2_b + l * HDIM,
            ff1_w_b + (size_t)l * FFN_DIM * HDIM, ff1_b + l * FFN_DIM,
            ffb, nullptr, FFN_DIM, HDIM);
        // h += ffb @ ff2_w^T + ff2_b
        gemm64<3><<<dim3(4, 128), blk, 0, stream>>>(
            ffb, ff2_w_b + (size_t)l * HDIM * FFN_DIM, ff2_b + l * HDIM, h,
            HDIM, FFN_DIM, FFN_DIM, FFN_DIM, 0.f);
    }

    // out = LNf(h) @ w_out^T + b_out   (fp32)
    gemm_ln<4, 64><<<dim3(4, 64), blk, 0, stream>>>(
        h, lnf_g, lnf_b, w_out_b, b_out, nullptr, (float*)d_out, HDIM, HDIM);
}